// Round 1
// baseline (1671.134 us; speedup 1.0000x reference)
//
#include <hip/hip_runtime.h>

// GRU: B=256, T=2000, I=23, H=128, gate order r,z,n (PyTorch), then mean over T.
// Decomposition: 1 batch row per block (256 blocks, 1/CU), no cross-block comm.
// 768 threads = 12 waves: thread (g = t%384, half = t/384) computes a K-half
// (64 MACs) of gate row g. Weights in VGPRs; h broadcast from LDS; partials
// exchanged through LDS; 128-thread epilogue does sigmoid/tanh + h update.

#define Bb 256
#define Tt 2000
#define Ii 23
#define Hh 128
#define Gg 384  // 3*H

__global__ __launch_bounds__(768, 3)
void gru_fused(const float* __restrict__ x,     // [B,T,I]
               const float* __restrict__ W_ih,  // [3H,I]
               const float* __restrict__ W_hh,  // [3H,H]
               const float* __restrict__ b_ih,  // [3H]
               const float* __restrict__ b_hh,  // [3H]
               float* __restrict__ out)         // [B,H]
{
    const int b    = blockIdx.x;
    const int t    = threadIdx.x;      // 0..767
    const int g    = t % Gg;           // gate row
    const int half = t / Gg;           // 0 or 1 (K-half)
    const int kbase = half * 64;

    __shared__ float h_lds[Hh];        // current hidden state (fp32)
    __shared__ float rec[2][Gg];       // per-half partial sums
    __shared__ float gxn[Hh];          // input-side projection for n gate
    __shared__ float xbuf[2][24];      // double-buffered x_t

    // ---- weights to registers (one-time; L2-amortized across blocks) ----
    float w[64];
    #pragma unroll
    for (int k = 0; k < 64; ++k) w[k] = W_hh[(size_t)g * Hh + kbase + k];

    float wi[Ii];
    if (half == 0) {
        #pragma unroll
        for (int i = 0; i < Ii; ++i) wi[i] = W_ih[(size_t)g * Ii + i];
    }
    const float bih = b_ih[g];
    const float bhh = b_hh[g];
    // bias folded into accumulator init:
    //  r,z rows (g<256): half0 acc starts at b_ih+b_hh
    //  n rows (g>=256): recurrent acc starts at b_hh (stays inside gh_n),
    //                   input acc starts at b_ih (gx_n)
    const float rec_init = (half == 0) ? ((g < 2 * Hh) ? (bih + bhh) : bhh) : 0.0f;

    const float* xrow = x + (size_t)b * Tt * Ii;

    // ---- init ----
    if (t < Hh) h_lds[t] = 0.0f;
    if (t < Ii) xbuf[0][t] = xrow[t];
    float acc_mean = 0.0f;
    __syncthreads();

    for (int step = 0; step < Tt; ++step) {
        // prefetch next x_t into registers (latency hidden under dot loop)
        float xpref = 0.0f;
        if (t < Ii && step + 1 < Tt) xpref = xrow[(size_t)(step + 1) * Ii + t];

        // ---- recurrent dot: 64 MACs, h broadcast from LDS ----
        float racc = rec_init;
        const float* hp = h_lds + kbase;
        #pragma unroll
        for (int k = 0; k < 64; ++k) racc = fmaf(w[k], hp[k], racc);

        // ---- input-side dot (half0 only, 23 MACs) ----
        float gacc = 0.0f;
        if (half == 0) {
            const float* xb = xbuf[step & 1];
            if (g >= 2 * Hh) {               // n gate: keep gx separate
                gacc = bih;
                #pragma unroll
                for (int i = 0; i < Ii; ++i) gacc = fmaf(wi[i], xb[i], gacc);
            } else {                          // r,z: fold into combined sum
                #pragma unroll
                for (int i = 0; i < Ii; ++i) racc = fmaf(wi[i], xb[i], racc);
            }
        }

        rec[half][g] = racc;
        if (half == 0 && g >= 2 * Hh) gxn[g - 2 * Hh] = gacc;
        __syncthreads();

        // stage next x into the alternate LDS buffer
        if (t < Ii && step + 1 < Tt) xbuf[(step + 1) & 1][t] = xpref;

        // ---- epilogue: threads 0..127 update h ----
        if (t < Hh) {
            const int j = t;
            float s_r  = rec[0][j]          + rec[1][j];
            float s_z  = rec[0][Hh + j]     + rec[1][Hh + j];
            float ghn  = rec[0][2 * Hh + j] + rec[1][2 * Hh + j]; // incl b_hh
            float gxnv = gxn[j];                                   // incl b_ih
            float r = 1.0f / (1.0f + __expf(-s_r));
            float z = 1.0f / (1.0f + __expf(-s_z));
            float npre = fmaf(r, ghn, gxnv);
            // tanh(x) = 2*sigmoid(2x) - 1  (saturates cleanly at +/-inf)
            float n = 2.0f / (1.0f + __expf(-2.0f * npre)) - 1.0f;
            float h_old = h_lds[j];
            float h_new = fmaf(z, h_old - n, n);
            acc_mean += h_new;
            h_lds[j] = h_new;
        }
        __syncthreads();
    }

    if (t < Hh) out[(size_t)b * Hh + t] = acc_mean * (1.0f / Tt);
}

extern "C" void kernel_launch(void* const* d_in, const int* in_sizes, int n_in,
                              void* d_out, int out_size, void* d_ws, size_t ws_size,
                              hipStream_t stream) {
    const float* x    = (const float*)d_in[0];
    const float* W_ih = (const float*)d_in[1];
    const float* W_hh = (const float*)d_in[2];
    const float* b_ih = (const float*)d_in[3];
    const float* b_hh = (const float*)d_in[4];
    float* out = (float*)d_out;

    gru_fused<<<Bb, 768, 0, stream>>>(x, W_ih, W_hh, b_ih, b_hh, out);
}